// Round 4
// baseline (1516.304 us; speedup 1.0000x reference)
//
#include <hip/hip_runtime.h>

// RSNEncoder R4: persistent-M gates kernel (grid=256, 4 chunks/block) with
// continuous counted-vmcnt pipeline across chunk boundaries; epilogue overlaps
// next-chunk prefetch. Mixed GEMM as R3. T1 XCD swizzle, T2 LDS swizzle, T5.

#define BDIM 32768
#define DDIM 512
#define BD (BDIM * DDIM)

typedef short bf16x8 __attribute__((ext_vector_type(8)));
typedef float f32x4 __attribute__((ext_vector_type(4)));
typedef unsigned short u16x8 __attribute__((ext_vector_type(8)));

#define AS1 __attribute__((address_space(1)))
#define AS3 __attribute__((address_space(3)))

__device__ __forceinline__ unsigned short f2bf(float f) {
  union { float f; unsigned u; } v; v.f = f;
  return (unsigned short)((v.u + 0x7fffu + ((v.u >> 16) & 1u)) >> 16);  // RNE
}
__device__ __forceinline__ float bf2f(unsigned short b) {
  union { unsigned u; float f; } v; v.u = (unsigned)b << 16; return v.f;
}
__device__ __forceinline__ float sigmf(float x) { return 1.0f / (1.0f + __expf(-x)); }
__device__ __forceinline__ float tanhf_(float x) { return 1.0f - 2.0f / (__expf(2.0f * x) + 1.0f); }
__device__ __forceinline__ void bar() { asm volatile("s_barrier" ::: "memory"); }
#define VMCNT(n) asm volatile("s_waitcnt vmcnt(" #n ")" ::: "memory")

// ---- fp32 -> bf16 (all 8 steps; 8 elems/thread/iter) ----
__global__ void cvt_bf16_all(const float* __restrict__ in, unsigned short* __restrict__ out) {
  const size_t stride = (size_t)gridDim.x * 256;
  for (size_t i = (size_t)blockIdx.x * 256 + threadIdx.x; i < (size_t)BD; i += stride) {
    const size_t o = i * 8;
    const float4 a = *(const float4*)(in + o);
    const float4 b = *(const float4*)(in + o + 4);
    u16x8 v;
    v[0] = f2bf(a.x); v[1] = f2bf(a.y); v[2] = f2bf(a.z); v[3] = f2bf(a.w);
    v[4] = f2bf(b.x); v[5] = f2bf(b.y); v[6] = f2bf(b.z); v[7] = f2bf(b.w);
    *(u16x8*)(out + o) = v;
  }
}

// ---- weight prep: Wg[1536][1024] = [Wih | Whh] (rows r,z,n); Wm[512][1024] = [w1 | w2] ----
__global__ void prep_w(const float* __restrict__ wih, const float* __restrict__ whh,
                       const float* __restrict__ w1, const float* __restrict__ w2,
                       unsigned short* __restrict__ Wg, unsigned short* __restrict__ Wm) {
  int i = blockIdx.x * 256 + threadIdx.x;
  if (i < 1536 * 1024) {
    const int j = i >> 10, k = i & 1023;
    Wg[i] = f2bf((k < 512) ? wih[j * 512 + k] : whh[j * 512 + (k - 512)]);
  } else {
    i -= 1536 * 1024;
    const int j = i >> 10, k = i & 1023;
    Wm[i] = f2bf((k < 512) ? w1[j * 512 + k] : w2[j * 512 + (k - 512)]);
  }
}

template <int SET>
__device__ __forceinline__ void mfma16(f32x4 (&acc)[4][4][2], const bf16x8 (&av)[4][2],
                                       const bf16x8 (&bv)[2][2]) {
  __builtin_amdgcn_s_setprio(1);
#pragma unroll
  for (int fm = 0; fm < 4; ++fm)
#pragma unroll
    for (int fn = 0; fn < 2; ++fn)
#pragma unroll
      for (int ks = 0; ks < 2; ++ks)
        acc[SET][fm][fn] = __builtin_amdgcn_mfma_f32_16x16x32_bf16(
            av[fm][ks], bv[fn][ks], acc[SET][fm][fn], 0, 0, 0);
  __builtin_amdgcn_s_setprio(0);
}

// ================= gates kernel (persistent-M) =================
// grid = 256 blocks (1/CU). Block: bn in [0,8) d-block, 4 chunks of 256 rows.
// bm(q) = xcd*16 + q*4 + mslot. Per chunk: 16 K-tiles x 3 phases (r,z,n).
__global__ __launch_bounds__(512, 2) void gru_gates(
    const unsigned short* __restrict__ X, const unsigned short* __restrict__ H,
    const unsigned short* __restrict__ Wg, const float* __restrict__ bih,
    const float* __restrict__ bhh, unsigned short* __restrict__ outB) {
  __shared__ char smem[114688];
  const int t = threadIdx.x;
  const int lane = t & 63, wid = t >> 6;
  const int wm = wid >> 1, wn = wid & 1;  // wave tile 64 rows x 32 cols
  const int xcd = blockIdx.x & 7, ixc = blockIdx.x >> 3;
  const int bn = ixc & 7;
  const int mslot = ixc >> 3;  // 0..3

  f32x4 acc[4][4][2];
  const f32x4 z4 = {0.f, 0.f, 0.f, 0.f};
#pragma unroll
  for (int s = 0; s < 4; ++s)
#pragma unroll
    for (int a = 0; a < 4; ++a)
#pragma unroll
      for (int b = 0; b < 2; ++b) acc[s][a][b] = z4;

  const int trow = t >> 3;
  const int tswz = ((t & 7) * 16) ^ ((trow & 7) << 4);
  int asrc[4], bsrc[3];
#pragma unroll
  for (int i = 0; i < 4; ++i) asrc[i] = (i * 64 + trow) * 1024 + tswz;  // chunk-relative
#pragma unroll
  for (int g = 0; g < 3; ++g) bsrc[g] = (g * 512 + bn * 64 + trow) * 2048 + tswz;

  const char* Xc = (const char*)X;
  const char* Hc = (const char*)H;
  const char* Wc = (const char*)Wg;

  auto mbase = [&](int q) -> size_t {
    return (size_t)(xcd * 16 + q * 4 + mslot) << 18;  // bm * 256 rows * 1024 B
  };
  // issue A piece i of tile (chunk q, kt); kt<8 -> X half, kt>=8 -> H half
  auto issA = [&](int q, int kt, int i) {
    const char* base = ((kt < 8) ? Xc : Hc) + mbase(q) + (kt & 7) * 128 + asrc[i];
    char* dst = smem + (kt & 1) * 57344 + i * 8192 + t * 16;
    __builtin_amdgcn_global_load_lds((const AS1 void*)base, (AS3 void*)dst, 16, 0, 0);
  };
  auto issB = [&](int kt, int g) {
    const char* base = Wc + (kt & 15) * 128 + bsrc[g];
    char* dst = smem + (kt & 1) * 57344 + 32768 + g * 8192 + t * 16;
    __builtin_amdgcn_global_load_lds((const AS1 void*)base, (AS3 void*)dst, 16, 0, 0);
  };

  bf16x8 av[4][2], bv[2][2];
  auto readA = [&](const char* pa) {
#pragma unroll
    for (int fm = 0; fm < 4; ++fm)
#pragma unroll
      for (int ks = 0; ks < 2; ++ks) {
        const int r = wm * 64 + fm * 16 + (lane & 15);
        const int c = ks * 64 + (lane >> 4) * 16;
        av[fm][ks] = *(const bf16x8*)(pa + r * 128 + (c ^ ((r & 7) << 4)));
      }
  };
  auto readB = [&](const char* pb, int g) {
#pragma unroll
    for (int fn = 0; fn < 2; ++fn)
#pragma unroll
      for (int ks = 0; ks < 2; ++ks) {
        const int r = wn * 32 + fn * 16 + (lane & 15);
        const int c = ks * 64 + (lane >> 4) * 16;
        bv[fn][ks] = *(const bf16x8*)(pb + g * 8192 + r * 128 + (c ^ ((r & 7) << 4)));
      }
  };

  const int erow = (lane >> 4) * 4, ecol = lane & 15;

  // prologue: tile (0,0): A0..3,B0,B1,B2 -> vmcnt(2): A+B0 arrived, B1,B2 in flight
  issA(0, 0, 0); issA(0, 0, 1); issA(0, 0, 2); issA(0, 0, 3);
  issB(0, 0); issB(0, 1); issB(0, 2);
  VMCNT(2);
  bar();

#pragma unroll 1
  for (int q = 0; q < 4; ++q) {
#pragma unroll 2
    for (int kt = 0; kt < 16; ++kt) {
      const bool lastT = (kt == 15);
      const bool lastC = (q == 3);
      const bool bnd0 = (kt == 0) && (q > 0);  // tile 0 after boundary: already issued
      const char* pa = smem + (kt & 1) * 57344;
      const char* pb = pa + 32768;
      // ---- phase 0: gate r ----
      readA(pa);
      readB(pb, 0);
      if (!lastT) {
        if (!bnd0) { issA(q, kt + 1, 0); issA(q, kt + 1, 1); issA(q, kt + 1, 2); VMCNT(4); }
      } else if (!lastC) {
        issA(q + 1, 0, 0); issA(q + 1, 0, 1); issA(q + 1, 0, 2); VMCNT(4);
      } else {
        VMCNT(1);
      }
      bar();
      mfma16<0>(acc, av, bv);
      bar();
      // ---- phase 1: gate z ----
      readB(pb, 1);
      if (!lastT) {
        if (!bnd0) { issA(q, kt + 1, 3); issB(kt + 1, 0); VMCNT(5); }
      } else if (!lastC) {
        issA(q + 1, 0, 3); issB(16, 0);  // tile 0 of next chunk (kt&15 -> 0, buf 0)
        VMCNT(5);
      } else {
        VMCNT(0);
      }
      bar();
      mfma16<1>(acc, av, bv);
      bar();
      // ---- phase 2: gate n ----
      readB(pb, 2);
      if (!lastT) {
        issB(kt + 1, 1); issB(kt + 1, 2); VMCNT(2);
      } else if (!lastC) {
        issB(16, 1); issB(16, 2); VMCNT(2);
      }
      bar();
      if (kt < 8) mfma16<2>(acc, av, bv);  // i_n (K<512)
      else        mfma16<3>(acc, av, bv);  // h_n (K>=512)
      bar();
    }

    // ---- epilogue for chunk q (overlaps in-flight prefetch of chunk q+1) ----
    const int rbase = (xcd * 16 + q * 4 + mslot) * 256 + wm * 64;
#pragma unroll
    for (int fn = 0; fn < 2; ++fn) {
      const int d = bn * 64 + wn * 32 + fn * 16 + ecol;
      const float br = bih[d] + bhh[d];
      const float bz = bih[512 + d] + bhh[512 + d];
      const float bi = bih[1024 + d];
      const float bh = bhh[1024 + d];
#pragma unroll
      for (int fm = 0; fm < 4; ++fm)
#pragma unroll
        for (int j = 0; j < 4; ++j) {
          const size_t off = (size_t)(rbase + fm * 16 + erow + j) * 512 + d;
          const float rv = sigmf(acc[0][fm][fn][j] + br);
          const float zv = sigmf(acc[1][fm][fn][j] + bz);
          const float nv = tanhf_(acc[2][fm][fn][j] + bi + rv * (acc[3][fm][fn][j] + bh));
          outB[off] = f2bf((1.0f - zv) * nv + zv * bf2f(H[off]));
        }
    }

    if (q < 3) {
      // reset accumulators for next chunk
#pragma unroll
      for (int s = 0; s < 4; ++s)
#pragma unroll
        for (int a = 0; a < 4; ++a)
#pragma unroll
          for (int b = 0; b < 2; ++b) acc[s][a][b] = z4;
      VMCNT(0);  // drain epilogue stores (+ B1,B2 of next tile 0, long arrived)
      // issue tile 1 of next chunk fully (tile 0 already resident in buf 0)
      issA(q + 1, 1, 0); issA(q + 1, 1, 1); issA(q + 1, 1, 2); issA(q + 1, 1, 3);
      issB(1, 0); issB(1, 1); issB(1, 2);
      // no wait: tile-0 phases run ~1.9K cyc before tile 1 is read (p2 VMCNT(2) certifies)
    }
  }
}

// ================= mixed kernel: out = A @ [w1|w2]^T (unchanged R3) =================
template <int MH, int NH>
__device__ __forceinline__ void mfmaQ(f32x4 (&acc)[8][4], const bf16x8 (&af)[4][2],
                                      const bf16x8 (&bv)[2][2]) {
  __builtin_amdgcn_s_setprio(1);
#pragma unroll
  for (int fm = 0; fm < 4; ++fm)
#pragma unroll
    for (int fn = 0; fn < 2; ++fn)
#pragma unroll
      for (int ks = 0; ks < 2; ++ks)
        acc[MH * 4 + fm][NH * 2 + fn] = __builtin_amdgcn_mfma_f32_16x16x32_bf16(
            af[fm][ks], bv[fn][ks], acc[MH * 4 + fm][NH * 2 + fn], 0, 0, 0);
  __builtin_amdgcn_s_setprio(0);
}

template <int WF>
__global__ __launch_bounds__(512, 2) void mixed_gemm(
    const unsigned short* __restrict__ Ka, const unsigned short* __restrict__ Kb,
    const unsigned short* __restrict__ Wm,
    unsigned short* __restrict__ outB, float* __restrict__ outF) {
  __shared__ char smem[131072];
  const int t = threadIdx.x;
  const int lane = t & 63, wid = t >> 6;
  const int wm = wid >> 2, wn = wid & 3;
  const int xcd = blockIdx.x & 7, ixc = blockIdx.x >> 3;
  const int bm = xcd * 16 + (ixc >> 1);
  const int bn = ixc & 1;

  f32x4 acc[8][4];
  const f32x4 z4 = {0.f, 0.f, 0.f, 0.f};
#pragma unroll
  for (int a = 0; a < 8; ++a)
#pragma unroll
    for (int b = 0; b < 4; ++b) acc[a][b] = z4;

  const int trow = t >> 3;
  const int tswz = ((t & 7) * 16) ^ ((trow & 7) << 4);
  int asrc[4], bsrc[4];
#pragma unroll
  for (int i = 0; i < 4; ++i) {
    asrc[i] = (bm * 256 + i * 64 + trow) * 1024 + tswz;
    bsrc[i] = (bn * 256 + i * 64 + trow) * 2048 + tswz;
  }
  const char* Kac = (const char*)Ka;
  const char* Kbc = (const char*)Kb;
  const char* Wc = (const char*)Wm;

  auto issA = [&](int kt, int i) {
    const char* base = ((kt < 8) ? Kac : Kbc) + (kt & 7) * 128 + asrc[i];
    char* dst = smem + (kt & 1) * 65536 + i * 8192 + t * 16;
    __builtin_amdgcn_global_load_lds((const AS1 void*)base, (AS3 void*)dst, 16, 0, 0);
  };
  auto issB = [&](int kt, int i) {
    const char* base = Wc + kt * 128 + bsrc[i];
    char* dst = smem + (kt & 1) * 65536 + 32768 + i * 8192 + t * 16;
    __builtin_amdgcn_global_load_lds((const AS1 void*)base, (AS3 void*)dst, 16, 0, 0);
  };

  bf16x8 af[4][2], bf0[2][2], bf1[2][2];
  auto readAm = [&](const char* pa, int mh) {
#pragma unroll
    for (int fm = 0; fm < 4; ++fm)
#pragma unroll
      for (int ks = 0; ks < 2; ++ks) {
        const int r = mh * 128 + wm * 64 + fm * 16 + (lane & 15);
        const int c = ks * 64 + (lane >> 4) * 16;
        af[fm][ks] = *(const bf16x8*)(pa + r * 128 + (c ^ ((r & 7) << 4)));
      }
  };
  auto readBm = [&](const char* pb, int nh, bf16x8 (&bv)[2][2]) {
#pragma unroll
    for (int fn = 0; fn < 2; ++fn)
#pragma unroll
      for (int ks = 0; ks < 2; ++ks) {
        const int r = nh * 128 + wn * 32 + fn * 16 + (lane & 15);
        const int c = ks * 64 + (lane >> 4) * 16;
        bv[fn][ks] = *(const bf16x8*)(pb + r * 128 + (c ^ ((r & 7) << 4)));
      }
  };

  issA(0, 0); issA(0, 1); issB(0, 0); issB(0, 1);
  issB(0, 2); issB(0, 3); issA(0, 2); issA(0, 3);
  VMCNT(4);
  bar();

  for (int kt = 0; kt < 16; ++kt) {
    const bool last = (kt == 15);
    const char* pa = smem + (kt & 1) * 65536;
    const char* pb = pa + 32768;
    readAm(pa, 0);
    readBm(pb, 0, bf0);
    if (!last) { issA(kt + 1, 0); issA(kt + 1, 1); VMCNT(4); }
    else       { VMCNT(2); }
    bar();
    mfmaQ<0, 0>(acc, af, bf0);
    bar();
    readBm(pb, 1, bf1);
    if (!last) { issB(kt + 1, 0); issB(kt + 1, 1); VMCNT(4); }
    else       { VMCNT(0); }
    bar();
    mfmaQ<0, 1>(acc, af, bf1);
    bar();
    readAm(pa, 1);
    if (!last) { issB(kt + 1, 2); issB(kt + 1, 3); }
    bar();
    mfmaQ<1, 0>(acc, af, bf0);
    bar();
    if (!last) { issA(kt + 1, 2); issA(kt + 1, 3); VMCNT(4); }
    bar();
    mfmaQ<1, 1>(acc, af, bf1);
    bar();
  }

  const int erow = (lane >> 4) * 4, ecol = lane & 15;
#pragma unroll
  for (int mh = 0; mh < 2; ++mh)
#pragma unroll
    for (int fm = 0; fm < 4; ++fm)
#pragma unroll
      for (int nh = 0; nh < 2; ++nh)
#pragma unroll
        for (int fn = 0; fn < 2; ++fn) {
          const int col = bn * 256 + nh * 128 + wn * 32 + fn * 16 + ecol;
#pragma unroll
          for (int j = 0; j < 4; ++j) {
            const int row = bm * 256 + mh * 128 + wm * 64 + fm * 16 + erow + j;
            const size_t off = (size_t)row * 512 + col;
            const float v = acc[mh * 4 + fm][nh * 2 + fn][j];
            if constexpr (WF) outF[off] = v;
            else              outB[off] = f2bf(v);
          }
        }
}

extern "C" void kernel_launch(void* const* d_in, const int* in_sizes, int n_in,
                              void* d_out, int out_size, void* d_ws, size_t ws_size,
                              hipStream_t stream) {
  const float* x   = (const float*)d_in[0];
  const float* wih = (const float*)d_in[1];
  const float* whh = (const float*)d_in[2];
  const float* bih = (const float*)d_in[3];
  const float* bhh = (const float*)d_in[4];
  const float* w1  = (const float*)d_in[5];
  const float* w2  = (const float*)d_in[6];

  char* ws = (char*)d_ws;
  const size_t bd2 = (size_t)BD * 2;
  unsigned short* xall  = (unsigned short*)ws;                  // 8 x 32 MB
  unsigned short* hb[2] = {(unsigned short*)(ws + 8 * bd2),
                           (unsigned short*)(ws + 9 * bd2)};    // 32 MB each
  unsigned short* Wg = (unsigned short*)(ws + 10 * bd2);        // 3 MB
  unsigned short* Wm = Wg + 1536 * 1024;                        // 1 MB

  hipMemsetAsync(hb[0], 0, bd2, stream);  // h0 = 0
  cvt_bf16_all<<<2048, 256, 0, stream>>>(x, xall);
  prep_w<<<8192, 256, 0, stream>>>(wih, whh, w1, w2, Wg, Wm);

  int hp = 0;
  for (int i = 0; i < 8; ++i) {
    const unsigned short* xi = xall + (size_t)i * BD;
    gru_gates<<<256, 512, 0, stream>>>(xi, hb[hp], Wg, bih, bhh, hb[hp ^ 1]);
    hp ^= 1;
    if (i & 1) {
      const unsigned short* xprev = xall + (size_t)(i - 1) * BD;
      if (i == 7)
        mixed_gemm<1><<<256, 512, 0, stream>>>(hb[hp], xprev, Wm, nullptr, (float*)d_out);
      else
        mixed_gemm<0><<<256, 512, 0, stream>>>(hb[hp], xprev, Wm, hb[hp ^ 1], nullptr);
      if (i != 7) hp ^= 1;
    }
  }
}